// Round 1
// baseline (2503.657 us; speedup 1.0000x reference)
//
#include <hip/hip_runtime.h>

static constexpr int N  = 98304;
static constexpr int D  = 128;
static constexpr int E  = 491520;
static constexpr int B  = 16384;
static constexpr int TE = 16;   // edges per block in edge kernel

__global__ void copy_f4_kernel(const float4* __restrict__ src, float4* __restrict__ dst, int n4) {
    int i = blockIdx.x * blockDim.x + threadIdx.x;
    int stride = gridDim.x * blockDim.x;
    for (; i < n4; i += stride) dst[i] = src[i];
}

__global__ void zero_kernel(float* __restrict__ p, int n) {
    int i = blockIdx.x * blockDim.x + threadIdx.x;
    int stride = gridDim.x * blockDim.x;
    for (; i < n; i += stride) p[i] = 0.f;
}

// One block: 128 threads, TE=16 edges. Thread t computes output dim d=t for all 16 edges.
__global__ __launch_bounds__(128) void edge_kernel(
    const float* __restrict__ src,   // [N, D] pre-round latents (read-only)
    float* __restrict__ dst,         // [N, D] accumulator (pre-initialized to src copy)
    const float* __restrict__ Wm_r,  // [D, 2D] row-major
    const float* __restrict__ bm_r,  // [D]
    const int* __restrict__ efrom,
    const int* __restrict__ eto,
    const int* __restrict__ ch_ptr)
{
    __shared__ float h[TE][2 * D];   // 16 KB
    __shared__ int ef[TE], et[TE];
    const int t = threadIdx.x;
    const int e0 = blockIdx.x * TE;

    if (t < TE) { ef[t] = efrom[e0 + t]; et[t] = eto[e0 + t]; }
    __syncthreads();

    // Stage h-tile: h[e][0:128] = latents[from], h[e][128:256] = latents[to]; float4 coalesced.
    float4* h4 = reinterpret_cast<float4*>(&h[0][0]);
    const float4* src4 = reinterpret_cast<const float4*>(src);
    #pragma unroll
    for (int i = t; i < TE * 64; i += 128) {
        int e = i >> 6, q = i & 63;
        int node = (q < 32) ? ef[e] : et[e];
        h4[i] = src4[(size_t)node * 32 + (q & 31)];
    }
    __syncthreads();

    const int d = t;  // 0..127
    float acc[TE];
    #pragma unroll
    for (int e = 0; e < TE; ++e) acc[e] = 0.f;

    const float4* w4 = reinterpret_cast<const float4*>(Wm_r + (size_t)d * (2 * D));
    for (int k4 = 0; k4 < (2 * D) / 4; ++k4) {
        float4 wv = w4[k4];
        #pragma unroll
        for (int e = 0; e < TE; ++e) {
            float4 hv = reinterpret_cast<const float4*>(&h[e][0])[k4];
            acc[e] = fmaf(hv.x, wv.x, acc[e]);
            acc[e] = fmaf(hv.y, wv.y, acc[e]);
            acc[e] = fmaf(hv.z, wv.z, acc[e]);
            acc[e] = fmaf(hv.w, wv.w, acc[e]);
        }
    }

    const float scale = 1.0f / (float)(ch_ptr[0] - 1);
    const float bias = bm_r[d];
    #pragma unroll
    for (int e = 0; e < TE; ++e) {
        float m = acc[e] + bias;
        m = (m > 0.f) ? m * scale : 0.f;
        atomicAdd(&dst[(size_t)et[e] * D + d], m);
    }
}

__global__ __launch_bounds__(128) void segsum_kernel(
    const float* __restrict__ lat, const int* __restrict__ view, float* __restrict__ y)
{
    const int n = blockIdx.x;
    const int v = view[n];
    atomicAdd(&y[(size_t)v * D + threadIdx.x], lat[(size_t)n * D + threadIdx.x]);
}

// y (=d_out) holds segment sums on entry; overwritten with final output.
__global__ __launch_bounds__(128) void readout_kernel(
    float* __restrict__ y, const float* __restrict__ W1, const float* __restrict__ b1,
    const float* __restrict__ W2, const float* __restrict__ b2)
{
    __shared__ float yrow[D];
    __shared__ float hrow[D];
    const int b = blockIdx.x, t = threadIdx.x;
    yrow[t] = y[(size_t)b * D + t];
    __syncthreads();

    float a = 0.f;
    {
        const float4* w4 = reinterpret_cast<const float4*>(W1 + (size_t)t * D);
        const float4* y4 = reinterpret_cast<const float4*>(yrow);
        #pragma unroll
        for (int k = 0; k < D / 4; ++k) {
            float4 wv = w4[k], yv = y4[k];
            a = fmaf(wv.x, yv.x, a); a = fmaf(wv.y, yv.y, a);
            a = fmaf(wv.z, yv.z, a); a = fmaf(wv.w, yv.w, a);
        }
    }
    hrow[t] = fmaxf(a + b1[t], 0.f);
    __syncthreads();

    float o = 0.f;
    {
        const float4* w4 = reinterpret_cast<const float4*>(W2 + (size_t)t * D);
        const float4* h4 = reinterpret_cast<const float4*>(hrow);
        #pragma unroll
        for (int k = 0; k < D / 4; ++k) {
            float4 wv = w4[k], hv = h4[k];
            o = fmaf(wv.x, hv.x, o); o = fmaf(wv.y, hv.y, o);
            o = fmaf(wv.z, hv.z, o); o = fmaf(wv.w, hv.w, o);
        }
    }
    y[(size_t)b * D + t] = o + b2[t];
}

extern "C" void kernel_launch(void* const* d_in, const int* in_sizes, int n_in,
                              void* d_out, int out_size, void* d_ws, size_t ws_size,
                              hipStream_t stream) {
    const float* latents = (const float*)d_in[0];
    const float* Wm      = (const float*)d_in[1];  // [3, 128, 256]
    const float* bm      = (const float*)d_in[2];  // [3, 128]
    const float* W1      = (const float*)d_in[3];
    const float* b1      = (const float*)d_in[4];
    const float* W2      = (const float*)d_in[5];
    const float* b2      = (const float*)d_in[6];
    const int*   efrom   = (const int*)d_in[7];
    const int*   eto     = (const int*)d_in[8];
    const int*   view    = (const int*)d_in[9];
    const int*   ch      = (const int*)d_in[10];

    float* bufA = (float*)d_ws;                 // [N, D]
    float* bufB = bufA + (size_t)N * D;         // [N, D]
    float* out  = (float*)d_out;                // reused as y then final output

    const int n4 = N * D / 4;
    const int WMR = D * 2 * D;  // 32768 elems per round weight

    // Round 0: src = input latents, dst = bufA
    copy_f4_kernel<<<2048, 256, 0, stream>>>((const float4*)latents, (float4*)bufA, n4);
    edge_kernel<<<E / TE, 128, 0, stream>>>(latents, bufA, Wm, bm, efrom, eto, ch);
    // Round 1: src = bufA, dst = bufB
    copy_f4_kernel<<<2048, 256, 0, stream>>>((const float4*)bufA, (float4*)bufB, n4);
    edge_kernel<<<E / TE, 128, 0, stream>>>(bufA, bufB, Wm + WMR, bm + D, efrom, eto, ch);
    // Round 2: src = bufB, dst = bufA
    copy_f4_kernel<<<2048, 256, 0, stream>>>((const float4*)bufB, (float4*)bufA, n4);
    edge_kernel<<<E / TE, 128, 0, stream>>>(bufB, bufA, Wm + 2 * WMR, bm + 2 * D, efrom, eto, ch);

    // Readout: y = segment_sum(latents, view_id); out = relu(y@W1.T+b1)@W2.T+b2
    zero_kernel<<<2048, 256, 0, stream>>>(out, B * D);
    segsum_kernel<<<N, 128, 0, stream>>>(bufA, view, out);
    readout_kernel<<<B, 128, 0, stream>>>(out, W1, b1, W2, b2);
}

// Round 2
// 977.959 us; speedup vs baseline: 2.5601x; 2.5601x over previous
//
#include <hip/hip_runtime.h>

static constexpr int N  = 98304;
static constexpr int D  = 128;
static constexpr int E  = 491520;
static constexpr int B  = 16384;
static constexpr int EB = 64;    // edges per block in edge kernel

using f32x4 = __attribute__((ext_vector_type(4))) float;
using s16x8 = __attribute__((ext_vector_type(8))) short;

__device__ __forceinline__ ushort f2bf(float x) {
    unsigned u = __float_as_uint(x);
    unsigned r = (u + 0x7fffu + ((u >> 16) & 1u)) >> 16;
    return (ushort)r;
}

__global__ void copy_f4_kernel(const float4* __restrict__ src, float4* __restrict__ dst, int n4) {
    int i = blockIdx.x * blockDim.x + threadIdx.x;
    int stride = gridDim.x * blockDim.x;
    for (; i < n4; i += stride) dst[i] = src[i];
}

__global__ void zero_kernel(float* __restrict__ p, int n) {
    int i = blockIdx.x * blockDim.x + threadIdx.x;
    int stride = gridDim.x * blockDim.x;
    for (; i < n; i += stride) p[i] = 0.f;
}

// Convert Wm [3][128][256] fp32 -> bf16 in MFMA B-fragment order:
// Wb[r][(kt*8+nt)*64 + lane][j] = W[r][nt*16 + (lane&15)][kt*32 + (lane>>4)*8 + j]
__global__ void convW_kernel(const float* __restrict__ Wm, ushort* __restrict__ Wb) {
    int gid = blockIdx.x * 256 + threadIdx.x;
    if (gid >= 3 * 128 * 256) return;
    int r = gid >> 15;
    int rem = gid & 32767;
    int n = rem >> 8;
    int k = rem & 255;
    int kt = k >> 5, nt = n >> 4;
    int lane = (n & 15) + (((k & 31) >> 3) << 4);
    int j = k & 7;
    Wb[r * 32768 + ((kt * 8 + nt) * 64 + lane) * 8 + j] = f2bf(Wm[gid]);
}

// 256 threads = 4 waves; block handles 64 edges; wave w owns edges [w*16, w*16+16).
// Per wave: 8 n-tiles x 8 k-steps of mfma_f32_16x16x32_bf16.
__global__ __launch_bounds__(256) void edge_mfma_kernel(
    const float* __restrict__ src,    // [N, D] pre-round latents
    float* __restrict__ dst,          // [N, D] accumulator (pre-copied from src)
    const ushort* __restrict__ Wb,    // [128][256] bf16 in fragment order (this round)
    const float* __restrict__ bm_r,   // [D]
    const int* __restrict__ efrom,
    const int* __restrict__ eto,
    const int* __restrict__ ch_ptr)
{
    __shared__ ushort hs[EB * 256];   // 32 KB bf16 H tile, XOR-swizzled
    __shared__ int ef_s[EB], et_s[EB];
    const int t = threadIdx.x;
    const int e0 = blockIdx.x * EB;

    if (t < EB)            ef_s[t] = efrom[e0 + t];
    else if (t < 2 * EB)   et_s[t - EB] = eto[e0 + t - EB];
    __syncthreads();

    // Stage H = [lat[from] | lat[to]] as bf16. Chunk c: edge e=c>>5, q=c&31 covers
    // H[e][q*8 .. q*8+7] (q<16 -> from row, q>=16 -> to row; offsets line up).
    const float4* src4 = reinterpret_cast<const float4*>(src);
    char* hbase = reinterpret_cast<char*>(hs);
    #pragma unroll
    for (int it = 0; it < 8; ++it) {
        int c = t + it * 256;
        int e = c >> 5, q = c & 31;
        int node = (q < 16) ? ef_s[e] : et_s[e];
        float4 v0 = src4[(size_t)node * 32 + (q & 15) * 2];
        float4 v1 = src4[(size_t)node * 32 + (q & 15) * 2 + 1];
        union { s16x8 v; ushort u[8]; } pk;
        pk.u[0] = f2bf(v0.x); pk.u[1] = f2bf(v0.y); pk.u[2] = f2bf(v0.z); pk.u[3] = f2bf(v0.w);
        pk.u[4] = f2bf(v1.x); pk.u[5] = f2bf(v1.y); pk.u[6] = f2bf(v1.z); pk.u[7] = f2bf(v1.w);
        int bo = (q * 16) ^ ((e & 15) << 4);
        *reinterpret_cast<s16x8*>(hbase + e * 512 + bo) = pk.v;
    }
    __syncthreads();

    const int wave = t >> 6, lane = t & 63;
    const int erow = wave * 16 + (lane & 15);     // A-frag row = edge within block
    const int kq   = lane >> 4;                   // A-frag k-group
    const char* hrow = hbase + erow * 512;
    const int xorm = (erow & 15) << 4;

    f32x4 acc[8];
    #pragma unroll
    for (int nt = 0; nt < 8; ++nt) acc[nt] = (f32x4){0.f, 0.f, 0.f, 0.f};

    const s16x8* wf = reinterpret_cast<const s16x8*>(Wb);
    #pragma unroll
    for (int kt = 0; kt < 8; ++kt) {
        s16x8 a = *reinterpret_cast<const s16x8*>(hrow + ((kt * 64 + kq * 16) ^ xorm));
        #pragma unroll
        for (int nt = 0; nt < 8; ++nt) {
            s16x8 b = wf[(kt * 8 + nt) * 64 + lane];
            acc[nt] = __builtin_amdgcn_mfma_f32_16x16x32_bf16(a, b, acc[nt], 0, 0, 0);
        }
    }

    // Epilogue: C[m][n] mapping: col = lane&15 (+nt*16), row(edge) = (lane>>4)*4 + j.
    const float scale = 1.0f / (float)(ch_ptr[0] - 1);
    const int col = lane & 15;
    float bias[8];
    #pragma unroll
    for (int nt = 0; nt < 8; ++nt) bias[nt] = bm_r[nt * 16 + col];

    const int ebase = wave * 16 + (lane >> 4) * 4;
    #pragma unroll
    for (int j = 0; j < 4; ++j) {
        const int to = et_s[ebase + j];
        float* drow = dst + (size_t)to * 128 + col;
        #pragma unroll
        for (int nt = 0; nt < 8; ++nt) {
            float m = acc[nt][j] + bias[nt];
            m = (m > 0.f) ? m * scale : 0.f;
            atomicAdd(drow + nt * 16, m);
        }
    }
}

__global__ __launch_bounds__(128) void segsum_kernel(
    const float* __restrict__ lat, const int* __restrict__ view, float* __restrict__ y)
{
    const int n = blockIdx.x;
    const int v = view[n];
    atomicAdd(&y[(size_t)v * D + threadIdx.x], lat[(size_t)n * D + threadIdx.x]);
}

// y (=d_out) holds segment sums on entry; overwritten with final output.
__global__ __launch_bounds__(128) void readout_kernel(
    float* __restrict__ y, const float* __restrict__ W1, const float* __restrict__ b1,
    const float* __restrict__ W2, const float* __restrict__ b2)
{
    __shared__ float yrow[D];
    __shared__ float hrow[D];
    const int b = blockIdx.x, t = threadIdx.x;
    yrow[t] = y[(size_t)b * D + t];
    __syncthreads();

    float a = 0.f;
    {
        const float4* w4 = reinterpret_cast<const float4*>(W1 + (size_t)t * D);
        const float4* y4 = reinterpret_cast<const float4*>(yrow);
        #pragma unroll
        for (int k = 0; k < D / 4; ++k) {
            float4 wv = w4[k], yv = y4[k];
            a = fmaf(wv.x, yv.x, a); a = fmaf(wv.y, yv.y, a);
            a = fmaf(wv.z, yv.z, a); a = fmaf(wv.w, yv.w, a);
        }
    }
    hrow[t] = fmaxf(a + b1[t], 0.f);
    __syncthreads();

    float o = 0.f;
    {
        const float4* w4 = reinterpret_cast<const float4*>(W2 + (size_t)t * D);
        const float4* h4 = reinterpret_cast<const float4*>(hrow);
        #pragma unroll
        for (int k = 0; k < D / 4; ++k) {
            float4 wv = w4[k], hv = h4[k];
            o = fmaf(wv.x, hv.x, o); o = fmaf(wv.y, hv.y, o);
            o = fmaf(wv.z, hv.z, o); o = fmaf(wv.w, hv.w, o);
        }
    }
    y[(size_t)b * D + t] = o + b2[t];
}

extern "C" void kernel_launch(void* const* d_in, const int* in_sizes, int n_in,
                              void* d_out, int out_size, void* d_ws, size_t ws_size,
                              hipStream_t stream) {
    const float* latents = (const float*)d_in[0];
    const float* Wm      = (const float*)d_in[1];  // [3, 128, 256]
    const float* bm      = (const float*)d_in[2];  // [3, 128]
    const float* W1      = (const float*)d_in[3];
    const float* b1      = (const float*)d_in[4];
    const float* W2      = (const float*)d_in[5];
    const float* b2      = (const float*)d_in[6];
    const int*   efrom   = (const int*)d_in[7];
    const int*   eto     = (const int*)d_in[8];
    const int*   view    = (const int*)d_in[9];
    const int*   ch      = (const int*)d_in[10];

    float* bufA = (float*)d_ws;                 // [N, D]
    float* bufB = bufA + (size_t)N * D;         // [N, D]
    float* out  = (float*)d_out;

    // Stash bf16 fragment-ordered W in d_out (dead until the readout phase);
    // 3*32768 ushorts = 192 KB << B*D*4 = 8 MB. zero_kernel wipes it later.
    ushort* Wb = (ushort*)d_out;

    const int n4 = N * D / 4;

    convW_kernel<<<(3 * 128 * 256 + 255) / 256, 256, 0, stream>>>(Wm, Wb);

    // Round 0: src = input latents, dst = bufA
    copy_f4_kernel<<<2048, 256, 0, stream>>>((const float4*)latents, (float4*)bufA, n4);
    edge_mfma_kernel<<<E / EB, 256, 0, stream>>>(latents, bufA, Wb, bm, efrom, eto, ch);
    // Round 1: src = bufA, dst = bufB
    copy_f4_kernel<<<2048, 256, 0, stream>>>((const float4*)bufA, (float4*)bufB, n4);
    edge_mfma_kernel<<<E / EB, 256, 0, stream>>>(bufA, bufB, Wb + 32768, bm + D, efrom, eto, ch);
    // Round 2: src = bufB, dst = bufA
    copy_f4_kernel<<<2048, 256, 0, stream>>>((const float4*)bufB, (float4*)bufA, n4);
    edge_mfma_kernel<<<E / EB, 256, 0, stream>>>(bufB, bufA, Wb + 2 * 32768, bm + 2 * D, efrom, eto, ch);

    // Readout
    zero_kernel<<<2048, 256, 0, stream>>>(out, B * D);
    segsum_kernel<<<N, 128, 0, stream>>>(bufA, view, out);
    readout_kernel<<<B, 128, 0, stream>>>(out, W1, b1, W2, b2);
}

// Round 3
// 737.311 us; speedup vs baseline: 3.3957x; 1.3264x over previous
//
#include <hip/hip_runtime.h>

static constexpr int N  = 98304;
static constexpr int D  = 128;
static constexpr int E  = 491520;
static constexpr int B  = 16384;
static constexpr int EB = 64;    // edges per block in edge kernel

using f32x4 = __attribute__((ext_vector_type(4))) float;
using s16x8 = __attribute__((ext_vector_type(8))) short;

typedef __attribute__((address_space(3))) void lds_void;
typedef const __attribute__((address_space(1))) void gbl_void;

__device__ __forceinline__ ushort f2bf(float x) {
    unsigned u = __float_as_uint(x);
    return (ushort)((u + 0x7fffu + ((u >> 16) & 1u)) >> 16);
}

__global__ void zero_kernel(float* __restrict__ p, int n) {
    int i = blockIdx.x * blockDim.x + threadIdx.x;
    int stride = gridDim.x * blockDim.x;
    for (; i < n; i += stride) p[i] = 0.f;
}

// dst (fp32) = src; mir (bf16) = round(src). 8 floats per thread-iter.
__global__ void initcopy_kernel(const float4* __restrict__ src, float4* __restrict__ dst,
                                ushort* __restrict__ mir, int npair) {
    int i = blockIdx.x * blockDim.x + threadIdx.x;
    int stride = gridDim.x * blockDim.x;
    for (; i < npair; i += stride) {
        float4 a = src[2 * i], b = src[2 * i + 1];
        dst[2 * i] = a; dst[2 * i + 1] = b;
        union { s16x8 v; ushort u[8]; } pk;
        pk.u[0] = f2bf(a.x); pk.u[1] = f2bf(a.y); pk.u[2] = f2bf(a.z); pk.u[3] = f2bf(a.w);
        pk.u[4] = f2bf(b.x); pk.u[5] = f2bf(b.y); pk.u[6] = f2bf(b.z); pk.u[7] = f2bf(b.w);
        *reinterpret_cast<s16x8*>(mir + (size_t)i * 8) = pk.v;
    }
}

// mir (bf16) = round(src)
__global__ void mirror_kernel(const float4* __restrict__ src, ushort* __restrict__ mir, int npair) {
    int i = blockIdx.x * blockDim.x + threadIdx.x;
    int stride = gridDim.x * blockDim.x;
    for (; i < npair; i += stride) {
        float4 a = src[2 * i], b = src[2 * i + 1];
        union { s16x8 v; ushort u[8]; } pk;
        pk.u[0] = f2bf(a.x); pk.u[1] = f2bf(a.y); pk.u[2] = f2bf(a.z); pk.u[3] = f2bf(a.w);
        pk.u[4] = f2bf(b.x); pk.u[5] = f2bf(b.y); pk.u[6] = f2bf(b.z); pk.u[7] = f2bf(b.w);
        *reinterpret_cast<s16x8*>(mir + (size_t)i * 8) = pk.v;
    }
}

// Convert Wm [3][128][256] + W1 [128][128] + W2 [128][128] (fp32) -> bf16 fragment order.
// Frag layout: Wb[base + ((kt*8+nt)*64 + lane)*8 + j] = W[n][k],
//   n = nt*16 + (lane&15), k = kt*32 + ((lane>>4))*8 + j.
__global__ void convW_kernel(const float* __restrict__ Wm, const float* __restrict__ W1,
                             const float* __restrict__ W2, ushort* __restrict__ Wb) {
    int gid = blockIdx.x * 256 + threadIdx.x;
    if (gid < 3 * 32768) {
        int r = gid >> 15, rem = gid & 32767;
        int n = rem >> 8, k = rem & 255;
        int kt = k >> 5, nt = n >> 4;
        int lane = (n & 15) + (((k >> 3) & 3) << 4);
        int j = k & 7;
        Wb[r * 32768 + ((kt * 8 + nt) * 64 + lane) * 8 + j] = f2bf(Wm[gid]);
    } else if (gid < 3 * 32768 + 2 * 16384) {
        int gid2 = gid - 3 * 32768;
        int w = gid2 >> 14, rem = gid2 & 16383;
        int n = rem >> 7, k = rem & 127;
        int kt = k >> 5, nt = n >> 4;
        int lane = (n & 15) + (((k >> 3) & 3) << 4);
        int j = k & 7;
        const float* W = w ? W2 : W1;
        Wb[3 * 32768 + w * 16384 + ((kt * 8 + nt) * 64 + lane) * 8 + j] = f2bf(W[rem]);
    }
}

// 256 threads = 4 waves; 64 edges/block. Gathers bf16 mirror rows straight into
// LDS via global_load_lds (16B, source pre-swizzled so the linear LDS dest holds
// chunk p = g ^ (e&15)); MFMA 8kt x 8nt per wave; fp32 atomicAdd scatter.
__global__ __launch_bounds__(256) void edge_mfma_kernel(
    const ushort* __restrict__ mir,   // [N][128] bf16 snapshot of pre-round latents
    float* __restrict__ dst,          // [N][128] fp32 accumulator (current latents)
    const ushort* __restrict__ Wb,    // this round's frag-ordered weights
    const float* __restrict__ bm_r,   // [128]
    const int* __restrict__ efrom,
    const int* __restrict__ eto,
    const int* __restrict__ ch_ptr)
{
    __shared__ ushort hs[EB * 256];   // 32 KB: 64 rows x 512 B (32 chunks of 16B)
    __shared__ int ef_s[EB], et_s[EB];
    const int t = threadIdx.x;
    const int e0 = blockIdx.x * EB;

    if (t < EB)          ef_s[t] = efrom[e0 + t];
    else if (t < 2 * EB) et_s[t - EB] = eto[e0 + t - EB];
    __syncthreads();

    char* hbase = reinterpret_cast<char*>(hs);
    #pragma unroll
    for (int it = 0; it < 8; ++it) {
        int c = t + it * 256;          // chunk id: edge e = c>>5, LDS pos p = c&31
        int e = c >> 5, p = c & 31;
        int g = (p & 16) | ((p ^ e) & 15);   // global chunk (swizzle stays in half)
        int node = (p < 16) ? ef_s[e] : et_s[e];
        const char* gsrc = reinterpret_cast<const char*>(mir + (size_t)node * 128) + (g & 15) * 16;
        __builtin_amdgcn_global_load_lds((gbl_void*)gsrc, (lds_void*)(hbase + c * 16), 16, 0, 0);
    }
    __syncthreads();

    const int wave = t >> 6, lane = t & 63;
    const int erow = wave * 16 + (lane & 15);
    const int kq   = lane >> 4;
    const char* hrow = hbase + erow * 512;
    const int ex = erow & 15;

    f32x4 acc[8];
    #pragma unroll
    for (int nt = 0; nt < 8; ++nt) acc[nt] = (f32x4){0.f, 0.f, 0.f, 0.f};

    const s16x8* wf = reinterpret_cast<const s16x8*>(Wb);
    #pragma unroll
    for (int kt = 0; kt < 8; ++kt) {
        int C = kt * 4 + kq;
        s16x8 a = *reinterpret_cast<const s16x8*>(hrow + (((C & 16) | ((C ^ ex) & 15)) * 16));
        #pragma unroll
        for (int nt = 0; nt < 8; ++nt) {
            s16x8 b = wf[(kt * 8 + nt) * 64 + lane];
            acc[nt] = __builtin_amdgcn_mfma_f32_16x16x32_bf16(a, b, acc[nt], 0, 0, 0);
        }
    }

    const float scale = 1.0f / (float)(ch_ptr[0] - 1);
    const int col = lane & 15;
    float bias[8];
    #pragma unroll
    for (int nt = 0; nt < 8; ++nt) bias[nt] = bm_r[nt * 16 + col];

    const int ebase = wave * 16 + (lane >> 4) * 4;
    #pragma unroll
    for (int j = 0; j < 4; ++j) {
        const int to = et_s[ebase + j];
        float* drow = dst + (size_t)to * 128 + col;
        #pragma unroll
        for (int nt = 0; nt < 8; ++nt) {
            float m = acc[nt][j] + bias[nt];
            m = (m > 0.f) ? m * scale : 0.f;
            atomicAdd(drow + nt * 16, m);
        }
    }
}

__global__ __launch_bounds__(128) void segsum_kernel(
    const float* __restrict__ lat, const int* __restrict__ view, float* __restrict__ y)
{
    const int n = blockIdx.x;
    const int v = view[n];
    atomicAdd(&y[(size_t)v * D + threadIdx.x], lat[(size_t)n * D + threadIdx.x]);
}

// Fused readout: 64 y-rows per block. y (bf16, LDS) @ W1^T -> relu -> LDS -> @ W2^T -> d_out.
__global__ __launch_bounds__(256) void readout_mfma_kernel(
    float* __restrict__ y,            // d_out: [B][128] segment sums; overwritten in place
    const ushort* __restrict__ Wb1, const ushort* __restrict__ Wb2,
    const float* __restrict__ b1, const float* __restrict__ b2)
{
    __shared__ ushort hs[64 * 128];   // 16 KB: 64 rows x 256 B (16 chunks)
    const int t = threadIdx.x;
    const int r0 = blockIdx.x * 64;
    char* hbase = reinterpret_cast<char*>(hs);
    const float4* y4 = reinterpret_cast<const float4*>(y);

    // Stage y rows as bf16, swizzled: pos p holds chunk g = p ^ (e&15).
    #pragma unroll
    for (int it = 0; it < 4; ++it) {
        int c = t + it * 256;
        int e = c >> 4, p = c & 15;
        int g = p ^ (e & 15);
        float4 a = y4[(size_t)(r0 + e) * 32 + g * 2];
        float4 bq = y4[(size_t)(r0 + e) * 32 + g * 2 + 1];
        union { s16x8 v; ushort u[8]; } pk;
        pk.u[0] = f2bf(a.x); pk.u[1] = f2bf(a.y); pk.u[2] = f2bf(a.z); pk.u[3] = f2bf(a.w);
        pk.u[4] = f2bf(bq.x); pk.u[5] = f2bf(bq.y); pk.u[6] = f2bf(bq.z); pk.u[7] = f2bf(bq.w);
        *reinterpret_cast<s16x8*>(hbase + e * 256 + p * 16) = pk.v;
    }
    __syncthreads();

    const int wave = t >> 6, lane = t & 63;
    const int rrow = wave * 16 + (lane & 15);
    const int kq = lane >> 4;
    const int rx = rrow & 15;
    const char* hrow = hbase + rrow * 256;
    const int col16 = lane & 15;

    f32x4 acc[8];
    #pragma unroll
    for (int nt = 0; nt < 8; ++nt) acc[nt] = (f32x4){0.f, 0.f, 0.f, 0.f};
    const s16x8* wf1 = reinterpret_cast<const s16x8*>(Wb1);
    #pragma unroll
    for (int kt = 0; kt < 4; ++kt) {
        int C = kt * 4 + kq;
        s16x8 a = *reinterpret_cast<const s16x8*>(hrow + ((C ^ rx) & 15) * 16);
        #pragma unroll
        for (int nt = 0; nt < 8; ++nt)
            acc[nt] = __builtin_amdgcn_mfma_f32_16x16x32_bf16(a, wf1[(kt * 8 + nt) * 64 + lane], acc[nt], 0, 0, 0);
    }
    __syncthreads();   // all waves done reading y-tile before overwrite

    // h = relu(acc + b1) -> bf16 LDS (same swizzle scheme)
    #pragma unroll
    for (int nt = 0; nt < 8; ++nt) {
        float bias = b1[nt * 16 + col16];
        #pragma unroll
        for (int j = 0; j < 4; ++j) {
            int r = wave * 16 + (lane >> 4) * 4 + j;
            float h = fmaxf(acc[nt][j] + bias, 0.f);
            int colfull = nt * 16 + col16;
            int chunk = colfull >> 3;
            int bo = ((chunk ^ (r & 15)) * 16) + (colfull & 7) * 2;
            *reinterpret_cast<ushort*>(hbase + r * 256 + bo) = f2bf(h);
        }
    }
    __syncthreads();

    f32x4 acc2[8];
    #pragma unroll
    for (int nt = 0; nt < 8; ++nt) acc2[nt] = (f32x4){0.f, 0.f, 0.f, 0.f};
    const s16x8* wf2 = reinterpret_cast<const s16x8*>(Wb2);
    #pragma unroll
    for (int kt = 0; kt < 4; ++kt) {
        int C = kt * 4 + kq;
        s16x8 a = *reinterpret_cast<const s16x8*>(hrow + ((C ^ rx) & 15) * 16);
        #pragma unroll
        for (int nt = 0; nt < 8; ++nt)
            acc2[nt] = __builtin_amdgcn_mfma_f32_16x16x32_bf16(a, wf2[(kt * 8 + nt) * 64 + lane], acc2[nt], 0, 0, 0);
    }

    #pragma unroll
    for (int nt = 0; nt < 8; ++nt) {
        float bias = b2[nt * 16 + col16];
        #pragma unroll
        for (int j = 0; j < 4; ++j) {
            int r = r0 + wave * 16 + (lane >> 4) * 4 + j;
            y[(size_t)r * 128 + nt * 16 + col16] = acc2[nt][j] + bias;
        }
    }
}

extern "C" void kernel_launch(void* const* d_in, const int* in_sizes, int n_in,
                              void* d_out, int out_size, void* d_ws, size_t ws_size,
                              hipStream_t stream) {
    const float* latents = (const float*)d_in[0];
    const float* Wm      = (const float*)d_in[1];
    const float* bm      = (const float*)d_in[2];
    const float* W1      = (const float*)d_in[3];
    const float* b1      = (const float*)d_in[4];
    const float* W2      = (const float*)d_in[5];
    const float* b2      = (const float*)d_in[6];
    const int*   efrom   = (const int*)d_in[7];
    const int*   eto     = (const int*)d_in[8];
    const int*   view    = (const int*)d_in[9];
    const int*   ch      = (const int*)d_in[10];

    // Workspace layout: L fp32 [N*D] (50.3 MB) | mirror bf16 [N*D] (25.2 MB) | Wb (256 KB)
    float*  L   = (float*)d_ws;
    ushort* mir = (ushort*)(L + (size_t)N * D);
    ushort* Wb  = mir + (size_t)N * D;
    float*  out = (float*)d_out;

    const int npair = N * D / 8;

    convW_kernel<<<512, 256, 0, stream>>>(Wm, W1, W2, Wb);
    initcopy_kernel<<<2048, 256, 0, stream>>>((const float4*)latents, (float4*)L, mir, npair);

    edge_mfma_kernel<<<E / EB, 256, 0, stream>>>(mir, L, Wb, bm, efrom, eto, ch);
    mirror_kernel<<<2048, 256, 0, stream>>>((const float4*)L, mir, npair);
    edge_mfma_kernel<<<E / EB, 256, 0, stream>>>(mir, L, Wb + 32768, bm + D, efrom, eto, ch);
    mirror_kernel<<<2048, 256, 0, stream>>>((const float4*)L, mir, npair);
    edge_mfma_kernel<<<E / EB, 256, 0, stream>>>(mir, L, Wb + 2 * 32768, bm + 2 * D, efrom, eto, ch);

    zero_kernel<<<2048, 256, 0, stream>>>(out, B * D);
    segsum_kernel<<<N, 128, 0, stream>>>(L, view, out);
    readout_mfma_kernel<<<256, 256, 0, stream>>>(out, Wb + 98304, Wb + 98304 + 16384, b1, b2);
}

// Round 4
// 565.924 us; speedup vs baseline: 4.4240x; 1.3028x over previous
//
#include <hip/hip_runtime.h>

static constexpr int N  = 98304;
static constexpr int D  = 128;
static constexpr int E  = 491520;
static constexpr int B  = 16384;
static constexpr int EB = 64;    // edges per block in edge kernel

using f32x4 = __attribute__((ext_vector_type(4))) float;
using s16x8 = __attribute__((ext_vector_type(8))) short;

typedef __attribute__((address_space(3))) void lds_void;
typedef const __attribute__((address_space(1))) void gbl_void;

__device__ __forceinline__ ushort f2bf(float x) {
    unsigned u = __float_as_uint(x);
    return (ushort)((u + 0x7fffu + ((u >> 16) & 1u)) >> 16);
}

__global__ void zero_kernel(float* __restrict__ p, int n) {
    int i = blockIdx.x * blockDim.x + threadIdx.x;
    int stride = gridDim.x * blockDim.x;
    for (; i < n; i += stride) p[i] = 0.f;
}

__global__ void zero_int_kernel(int* __restrict__ p, int n) {
    int i = blockIdx.x * blockDim.x + threadIdx.x;
    int stride = gridDim.x * blockDim.x;
    for (; i < n; i += stride) p[i] = 0;
}

// ---- counting sort of edges by destination (runs once per launch) ----

__global__ void hist_kernel(const int* __restrict__ eto, int* __restrict__ cnt) {
    int e = blockIdx.x * 256 + threadIdx.x;
    if (e < E) atomicAdd(&cnt[eto[e]], 1);
}

// Per-block exclusive scan of 1024 ints; writes block total to bsum[b].
__global__ __launch_bounds__(256) void scan1_kernel(const int* __restrict__ cnt,
                                                    int* __restrict__ excl, int* __restrict__ bsum) {
    __shared__ int s[256];
    const int b = blockIdx.x, t = threadIdx.x;
    const int base = b * 1024 + t * 4;
    int4 v = *reinterpret_cast<const int4*>(cnt + base);
    int local = v.x + v.y + v.z + v.w;
    s[t] = local; __syncthreads();
    for (int off = 1; off < 256; off <<= 1) {
        int x = (t >= off) ? s[t - off] : 0;
        __syncthreads();
        s[t] += x;
        __syncthreads();
    }
    int excl_t = s[t] - local;
    if (t == 255) bsum[b] = s[t];
    int4 o;
    o.x = excl_t; o.y = o.x + v.x; o.z = o.y + v.y; o.w = o.z + v.z;
    *reinterpret_cast<int4*>(excl + base) = o;
}

// Exclusive scan of the 96 block sums (single block).
__global__ void scan2_kernel(int* __restrict__ bsum) {
    __shared__ int s[96];
    const int t = threadIdx.x;
    if (t < 96) s[t] = bsum[t];
    __syncthreads();
    if (t == 0) { int run = 0; for (int i = 0; i < 96; ++i) { int v = s[i]; s[i] = run; run += v; } }
    __syncthreads();
    if (t < 96) bsum[t] = s[t];
}

__global__ void scan3_kernel(int* __restrict__ excl, const int* __restrict__ bsum) {
    int i = blockIdx.x * 256 + threadIdx.x;
    excl[i] += bsum[i >> 10];
}

// cursor == excl; consumed here. Every slot [0,E) written exactly once.
__global__ void sortscatter_kernel(const int* __restrict__ efrom, const int* __restrict__ eto,
                                   int* __restrict__ cursor,
                                   int* __restrict__ sfrom, int* __restrict__ sto) {
    int e = blockIdx.x * 256 + threadIdx.x;
    if (e >= E) return;
    int to = eto[e];
    int p = atomicAdd(&cursor[to], 1);
    sfrom[p] = efrom[e];
    sto[p]   = to;
}

// ---- latent copies / bf16 mirror ----

__global__ void initcopy_kernel(const float4* __restrict__ src, float4* __restrict__ dst,
                                ushort* __restrict__ mir, int npair) {
    int i = blockIdx.x * blockDim.x + threadIdx.x;
    int stride = gridDim.x * blockDim.x;
    for (; i < npair; i += stride) {
        float4 a = src[2 * i], b = src[2 * i + 1];
        dst[2 * i] = a; dst[2 * i + 1] = b;
        union { s16x8 v; ushort u[8]; } pk;
        pk.u[0] = f2bf(a.x); pk.u[1] = f2bf(a.y); pk.u[2] = f2bf(a.z); pk.u[3] = f2bf(a.w);
        pk.u[4] = f2bf(b.x); pk.u[5] = f2bf(b.y); pk.u[6] = f2bf(b.z); pk.u[7] = f2bf(b.w);
        *reinterpret_cast<s16x8*>(mir + (size_t)i * 8) = pk.v;
    }
}

__global__ void mirror_kernel(const float4* __restrict__ src, ushort* __restrict__ mir, int npair) {
    int i = blockIdx.x * blockDim.x + threadIdx.x;
    int stride = gridDim.x * blockDim.x;
    for (; i < npair; i += stride) {
        float4 a = src[2 * i], b = src[2 * i + 1];
        union { s16x8 v; ushort u[8]; } pk;
        pk.u[0] = f2bf(a.x); pk.u[1] = f2bf(a.y); pk.u[2] = f2bf(a.z); pk.u[3] = f2bf(a.w);
        pk.u[4] = f2bf(b.x); pk.u[5] = f2bf(b.y); pk.u[6] = f2bf(b.z); pk.u[7] = f2bf(b.w);
        *reinterpret_cast<s16x8*>(mir + (size_t)i * 8) = pk.v;
    }
}

// Wm [3][128][256] + W1 [128][128] + W2 [128][128] fp32 -> bf16 MFMA B-fragment order.
__global__ void convW_kernel(const float* __restrict__ Wm, const float* __restrict__ W1,
                             const float* __restrict__ W2, ushort* __restrict__ Wb) {
    int gid = blockIdx.x * 256 + threadIdx.x;
    if (gid < 3 * 32768) {
        int r = gid >> 15, rem = gid & 32767;
        int n = rem >> 8, k = rem & 255;
        int kt = k >> 5, nt = n >> 4;
        int lane = (n & 15) + (((k >> 3) & 3) << 4);
        int j = k & 7;
        Wb[r * 32768 + ((kt * 8 + nt) * 64 + lane) * 8 + j] = f2bf(Wm[gid]);
    } else if (gid < 3 * 32768 + 2 * 16384) {
        int gid2 = gid - 3 * 32768;
        int w = gid2 >> 14, rem = gid2 & 16383;
        int n = rem >> 7, k = rem & 127;
        int kt = k >> 5, nt = n >> 4;
        int lane = (n & 15) + (((k >> 3) & 3) << 4);
        int j = k & 7;
        const float* W = w ? W2 : W1;
        Wb[3 * 32768 + w * 16384 + ((kt * 8 + nt) * 64 + lane) * 8 + j] = f2bf(W[rem]);
    }
}

// 256 threads = 4 waves; 64 DESTINATION-SORTED edges/block.
// global_load_lds bf16 gather -> MFMA -> per-edge msg to LDS -> run-reduce -> 1 atomic per run per dim.
__global__ __launch_bounds__(256) void edge_mfma_kernel(
    const ushort* __restrict__ mir,   // [N][128] bf16 snapshot of pre-round latents
    float* __restrict__ dst,          // [N][128] fp32 accumulator
    const ushort* __restrict__ Wb,
    const float* __restrict__ bm_r,
    const int* __restrict__ sfrom,    // sorted by destination
    const int* __restrict__ sto,
    const int* __restrict__ ch_ptr)
{
    __shared__ ushort hs[EB * 256];   // 32 KB; doubles as msg[64][128] f32 later
    __shared__ int ef_s[EB], et_s[EB];
    const int t = threadIdx.x;
    const int e0 = blockIdx.x * EB;

    if (t < EB)          ef_s[t] = sfrom[e0 + t];
    else if (t < 2 * EB) et_s[t - EB] = sto[e0 + t - EB];
    __syncthreads();

    char* hbase = reinterpret_cast<char*>(hs);
    #pragma unroll
    for (int it = 0; it < 8; ++it) {
        int c = t + it * 256;          // chunk id: edge e = c>>5, LDS pos p = c&31
        int e = c >> 5, p = c & 31;
        int g = (p & 16) | ((p ^ e) & 15);   // source chunk (XOR swizzle within half)
        int node = (p < 16) ? ef_s[e] : et_s[e];
        const char* gsrc = reinterpret_cast<const char*>(mir + (size_t)node * 128) + (g & 15) * 16;
        __builtin_amdgcn_global_load_lds((gbl_void*)gsrc, (lds_void*)(hbase + c * 16), 16, 0, 0);
    }
    __syncthreads();

    const int wave = t >> 6, lane = t & 63;
    const int erow = wave * 16 + (lane & 15);
    const int kq   = lane >> 4;
    const char* hrow = hbase + erow * 512;
    const int ex = erow & 15;

    f32x4 acc[8];
    #pragma unroll
    for (int nt = 0; nt < 8; ++nt) acc[nt] = (f32x4){0.f, 0.f, 0.f, 0.f};

    const s16x8* wf = reinterpret_cast<const s16x8*>(Wb);
    #pragma unroll
    for (int kt = 0; kt < 8; ++kt) {
        int C = kt * 4 + kq;
        s16x8 a = *reinterpret_cast<const s16x8*>(hrow + (((C & 16) | ((C ^ ex) & 15)) * 16));
        #pragma unroll
        for (int nt = 0; nt < 8; ++nt) {
            s16x8 b = wf[(kt * 8 + nt) * 64 + lane];
            acc[nt] = __builtin_amdgcn_mfma_f32_16x16x32_bf16(a, b, acc[nt], 0, 0, 0);
        }
    }

    // Per-edge message -> LDS (bias+relu+scale applied per-edge BEFORE summation).
    // msg layout: dword = row*128 + (col ^ (((row>>2)&3)<<4)) -> all 32 banks 2-way on
    // both write (4 row-groups x 16 cols) and read (64 consecutive cols) = conflict-free.
    // Intra-wave safe without a barrier: each wave reads/writes only its own 16 rows,
    // and lockstep execution orders all its A-frag ds_reads before these ds_writes.
    const float scale = 1.0f / (float)(ch_ptr[0] - 1);
    const int col = lane & 15;
    float bias[8];
    #pragma unroll
    for (int nt = 0; nt < 8; ++nt) bias[nt] = bm_r[nt * 16 + col];

    float* msgf = reinterpret_cast<float*>(hbase);
    const int ebase = wave * 16 + (lane >> 4) * 4;
    #pragma unroll
    for (int j = 0; j < 4; ++j) {
        const int row = ebase + j;
        const int xr = ((row >> 2) & 3) << 4;
        #pragma unroll
        for (int nt = 0; nt < 8; ++nt) {
            float m = acc[nt][j] + bias[nt];
            m = (m > 0.f) ? m * scale : 0.f;
            msgf[row * 128 + ((nt * 16 + col) ^ xr)] = m;
        }
    }
    __syncthreads();

    // Run-reduce: edges sorted by dest, so equal dests are contiguous. Each run head
    // sums its run and issues ONE atomic per dim. Control flow is wave-uniform
    // (et_s identical across lanes); d varies per lane -> coalesced atomics.
    const int d = t & 127;
    const int par = t >> 7;
    for (int i = par; i < EB; i += 2) {
        const int dest = et_s[i];
        if (i > 0 && et_s[i - 1] == dest) continue;   // not a run head
        float acc2 = msgf[i * 128 + (d ^ (((i >> 2) & 3) << 4))];
        int j2 = i + 1;
        while (j2 < EB && et_s[j2] == dest) {
            acc2 += msgf[j2 * 128 + (d ^ (((j2 >> 2) & 3) << 4))];
            ++j2;
        }
        atomicAdd(&dst[(size_t)dest * 128 + d], acc2);
    }
}

__global__ __launch_bounds__(128) void segsum_kernel(
    const float* __restrict__ lat, const int* __restrict__ view, float* __restrict__ y)
{
    const int n = blockIdx.x;
    const int v = view[n];
    atomicAdd(&y[(size_t)v * D + threadIdx.x], lat[(size_t)n * D + threadIdx.x]);
}

// Fused readout: 64 y-rows per block, two MFMA GEMMs through LDS.
__global__ __launch_bounds__(256) void readout_mfma_kernel(
    float* __restrict__ y,
    const ushort* __restrict__ Wb1, const ushort* __restrict__ Wb2,
    const float* __restrict__ b1, const float* __restrict__ b2)
{
    __shared__ ushort hs[64 * 128];
    const int t = threadIdx.x;
    const int r0 = blockIdx.x * 64;
    char* hbase = reinterpret_cast<char*>(hs);
    const float4* y4 = reinterpret_cast<const float4*>(y);

    #pragma unroll
    for (int it = 0; it < 4; ++it) {
        int c = t + it * 256;
        int e = c >> 4, p = c & 15;
        int g = p ^ (e & 15);
        float4 a = y4[(size_t)(r0 + e) * 32 + g * 2];
        float4 bq = y4[(size_t)(r0 + e) * 32 + g * 2 + 1];
        union { s16x8 v; ushort u[8]; } pk;
        pk.u[0] = f2bf(a.x); pk.u[1] = f2bf(a.y); pk.u[2] = f2bf(a.z); pk.u[3] = f2bf(a.w);
        pk.u[4] = f2bf(bq.x); pk.u[5] = f2bf(bq.y); pk.u[6] = f2bf(bq.z); pk.u[7] = f2bf(bq.w);
        *reinterpret_cast<s16x8*>(hbase + e * 256 + p * 16) = pk.v;
    }
    __syncthreads();

    const int wave = t >> 6, lane = t & 63;
    const int rrow = wave * 16 + (lane & 15);
    const int kq = lane >> 4;
    const int rx = rrow & 15;
    const char* hrow = hbase + rrow * 256;
    const int col16 = lane & 15;

    f32x4 acc[8];
    #pragma unroll
    for (int nt = 0; nt < 8; ++nt) acc[nt] = (f32x4){0.f, 0.f, 0.f, 0.f};
    const s16x8* wf1 = reinterpret_cast<const s16x8*>(Wb1);
    #pragma unroll
    for (int kt = 0; kt < 4; ++kt) {
        int C = kt * 4 + kq;
        s16x8 a = *reinterpret_cast<const s16x8*>(hrow + ((C ^ rx) & 15) * 16);
        #pragma unroll
        for (int nt = 0; nt < 8; ++nt)
            acc[nt] = __builtin_amdgcn_mfma_f32_16x16x32_bf16(a, wf1[(kt * 8 + nt) * 64 + lane], acc[nt], 0, 0, 0);
    }
    __syncthreads();

    #pragma unroll
    for (int nt = 0; nt < 8; ++nt) {
        float bias = b1[nt * 16 + col16];
        #pragma unroll
        for (int j = 0; j < 4; ++j) {
            int r = wave * 16 + (lane >> 4) * 4 + j;
            float h = fmaxf(acc[nt][j] + bias, 0.f);
            int colfull = nt * 16 + col16;
            int chunk = colfull >> 3;
            int bo = ((chunk ^ (r & 15)) * 16) + (colfull & 7) * 2;
            *reinterpret_cast<ushort*>(hbase + r * 256 + bo) = f2bf(h);
        }
    }
    __syncthreads();

    f32x4 acc2[8];
    #pragma unroll
    for (int nt = 0; nt < 8; ++nt) acc2[nt] = (f32x4){0.f, 0.f, 0.f, 0.f};
    const s16x8* wf2 = reinterpret_cast<const s16x8*>(Wb2);
    #pragma unroll
    for (int kt = 0; kt < 4; ++kt) {
        int C = kt * 4 + kq;
        s16x8 a = *reinterpret_cast<const s16x8*>(hrow + ((C ^ rx) & 15) * 16);
        #pragma unroll
        for (int nt = 0; nt < 8; ++nt)
            acc2[nt] = __builtin_amdgcn_mfma_f32_16x16x32_bf16(a, wf2[(kt * 8 + nt) * 64 + lane], acc2[nt], 0, 0, 0);
    }

    #pragma unroll
    for (int nt = 0; nt < 8; ++nt) {
        float bias = b2[nt * 16 + col16];
        #pragma unroll
        for (int j = 0; j < 4; ++j) {
            int r = r0 + wave * 16 + (lane >> 4) * 4 + j;
            y[(size_t)r * 128 + nt * 16 + col16] = acc2[nt][j] + bias;
        }
    }
}

extern "C" void kernel_launch(void* const* d_in, const int* in_sizes, int n_in,
                              void* d_out, int out_size, void* d_ws, size_t ws_size,
                              hipStream_t stream) {
    const float* latents = (const float*)d_in[0];
    const float* Wm      = (const float*)d_in[1];
    const float* bm      = (const float*)d_in[2];
    const float* W1      = (const float*)d_in[3];
    const float* b1      = (const float*)d_in[4];
    const float* W2      = (const float*)d_in[5];
    const float* b2      = (const float*)d_in[6];
    const int*   efrom   = (const int*)d_in[7];
    const int*   eto     = (const int*)d_in[8];
    const int*   view    = (const int*)d_in[9];
    const int*   ch      = (const int*)d_in[10];

    // ws layout: L f32[N*D] | mir bf16[N*D] | Wb ushort[131072] | cnt[N] | excl[N] | bsum[256] | sfrom[E] | sto[E]
    float*  L     = (float*)d_ws;
    ushort* mir   = (ushort*)(L + (size_t)N * D);
    ushort* Wb    = mir + (size_t)N * D;
    int*    cnt   = (int*)(Wb + 131072);
    int*    excl  = cnt + N;
    int*    bsum  = excl + N;
    int*    sfrom = bsum + 256;
    int*    sto   = sfrom + E;
    float*  out   = (float*)d_out;

    const int npair = N * D / 8;

    convW_kernel<<<512, 256, 0, stream>>>(Wm, W1, W2, Wb);
    initcopy_kernel<<<2048, 256, 0, stream>>>((const float4*)latents, (float4*)L, mir, npair);

    // Counting sort of edges by destination (message_to fixed across rounds).
    zero_int_kernel<<<512, 256, 0, stream>>>(cnt, N);
    hist_kernel<<<E / 256, 256, 0, stream>>>(eto, cnt);
    scan1_kernel<<<N / 1024, 256, 0, stream>>>(cnt, excl, bsum);
    scan2_kernel<<<1, 128, 0, stream>>>(bsum);
    scan3_kernel<<<N / 256, 256, 0, stream>>>(excl, bsum);
    sortscatter_kernel<<<E / 256, 256, 0, stream>>>(efrom, eto, excl, sfrom, sto);

    edge_mfma_kernel<<<E / EB, 256, 0, stream>>>(mir, L, Wb, bm, sfrom, sto, ch);
    mirror_kernel<<<2048, 256, 0, stream>>>((const float4*)L, mir, npair);
    edge_mfma_kernel<<<E / EB, 256, 0, stream>>>(mir, L, Wb + 32768, bm + D, sfrom, sto, ch);
    mirror_kernel<<<2048, 256, 0, stream>>>((const float4*)L, mir, npair);
    edge_mfma_kernel<<<E / EB, 256, 0, stream>>>(mir, L, Wb + 2 * 32768, bm + 2 * D, sfrom, sto, ch);

    zero_kernel<<<2048, 256, 0, stream>>>(out, B * D);
    segsum_kernel<<<N, 128, 0, stream>>>(L, view, out);
    readout_mfma_kernel<<<256, 256, 0, stream>>>(out, Wb + 98304, Wb + 98304 + 16384, b1, b2);
}